// Round 3
// baseline (210.932 us; speedup 1.0000x reference)
//
#include <hip/hip_runtime.h>
#include <stdint.h>

typedef __bf16 bf16x8 __attribute__((ext_vector_type(8)));
typedef float floatx4 __attribute__((ext_vector_type(4)));
typedef uint32_t uint32x4 __attribute__((ext_vector_type(4)));

#define GRID_W   15
#define PAD_W    17
#define CELLS    221            // 13*17 padded cells
#define HEXDIM   64
#define NHEX     165
#define OUTC     64
#define KDIM     448
#define CWORDS   32             // uint32 words per cell (64 bf16 = 8 chunks of 16B)
// XOR swizzle: physical chunk = logical chunk ^ (cell & 7). Keeps 16B alignment,
// rotates bank start across cells -> wave-wide b128 reads hit all 32 banks evenly.

// round-to-nearest-even fp32 -> bf16, packed pair
__device__ __forceinline__ uint32_t pack2bf(float a, float b) {
    union { float f; uint32_t u; } ua, ub;
    ua.f = a; ub.f = b;
    uint32_t ra = (ua.u + 0x7fffu + ((ua.u >> 16) & 1u)) >> 16;
    uint32_t rb = (ub.u + 0x7fffu + ((ub.u >> 16) & 1u)) >> 16;
    return ra | (rb << 16);
}

__global__ __launch_bounds__(256, 2)
void hexconv_kernel(const float* __restrict__ x,
                    const float* __restrict__ W,
                    const float* __restrict__ bias,
                    float* __restrict__ out)
{
    __shared__ __align__(16) uint32_t sx[CELLS * CWORDS]; // 28,288 B

    const int tid  = threadIdx.x;
    const int b    = blockIdx.x;
    const int wave = tid >> 6;
    const int lane = tid & 63;
    const int col  = lane & 15;   // A-row m / B-col (o) / C-col
    const int kq   = lane >> 4;   // k-quad: k = kq*8 + j
    const int ow   = wave & 1;    // o-half: owns out channels [ow*32, ow*32+32)
    const int mw   = wave >> 1;   // m-group: m-tiles mt = mw, mw+2, ...

    // ---- W B-fragments: 2 o-tiles x 14 k-steps, held in registers ----
    uint32x4 bw[2][14];
    float bias_o[2];
    #pragma unroll
    for (int ot = 0; ot < 2; ++ot) {
        const int o = ow * 32 + ot * 16 + col;
        const float* wrow = W + (size_t)o * KDIM + kq * 8;
        #pragma unroll
        for (int ks = 0; ks < 14; ++ks) {
            float4 v0 = *(const float4*)(wrow + ks * 32);
            float4 v1 = *(const float4*)(wrow + ks * 32 + 4);
            uint32x4 t;
            t[0] = pack2bf(v0.x, v0.y);
            t[1] = pack2bf(v0.z, v0.w);
            t[2] = pack2bf(v1.x, v1.y);
            t[3] = pack2bf(v1.z, v1.w);
            bw[ot][ks] = t;
        }
        bias_o[ot] = bias[o];
    }

    // ---- zero LDS (halo cells must read as 0) ----
    for (int i = tid; i < CELLS * CWORDS; i += 256) sx[i] = 0u;
    __syncthreads();

    // ---- stage sample b: fp32 global -> bf16 swizzled LDS grid ----
    {
        const float4* xs = (const float4*)(x + (size_t)b * NHEX * HEXDIM);
        for (int i = tid; i < NHEX * HEXDIM / 4; i += 256) {
            int n = i >> 4;            // 16 float4 per hex
            int d = i & 15;            // float4 index within hex
            float4 v = xs[i];
            int y0 = n / GRID_W, x0 = n - y0 * GRID_W;
            int cell = (y0 + 1) * PAD_W + (x0 + 1);
            int pc   = (d >> 1) ^ (cell & 7);               // swizzled 16B chunk
            uint32_t* dst = sx + cell * CWORDS + pc * 4 + (d & 1) * 2;
            uint2 p; p.x = pack2bf(v.x, v.y); p.y = pack2bf(v.z, v.w);
            *(uint2*)dst = p;
        }
    }
    __syncthreads();

    // ---- MFMA GEMM: out[n, o] = sum_k fc_in[n,k] * W[o,k] ----
    float* outb = out + (size_t)b * NHEX * OUTC;

    #pragma unroll 1
    for (int mt = mw; mt < 11; mt += 2) {
        int n = mt * 16 + col;           // A row this lane feeds
        bool valid = (n < NHEX);
        int nn = valid ? n : 0;
        int y0 = nn / GRID_W, x0 = nn - y0 * GRID_W;
        int base = (y0 + 1) * PAD_W + (x0 + 1);
        bool use0 = (y0 & 1);

        const int off0[7] = {-17, -16, -1, 0, 1, 17, 18};
        const int off1[7] = {-18, -17, -1, 0, 1, 16, 17};
        int cbase[7], csw[7];
        #pragma unroll
        for (int j = 0; j < 7; ++j) {
            int cell = valid ? (base + (use0 ? off0[j] : off1[j])) : 16; // cell 16 = halo (0)
            cbase[j] = cell * CWORDS;
            csw[j]   = cell & 7;
        }

        floatx4 acc0 = {0.f, 0.f, 0.f, 0.f};
        floatx4 acc1 = {0.f, 0.f, 0.f, 0.f};
        #pragma unroll
        for (int ks = 0; ks < 14; ++ks) {
            int j = ks >> 1;
            int chunk = ((ks & 1) * 4 + kq) ^ csw[j];
            uint32x4 av = *(const uint32x4*)(sx + cbase[j] + chunk * 4); // ds_read_b128
            bf16x8 a = __builtin_bit_cast(bf16x8, av);
            acc0 = __builtin_amdgcn_mfma_f32_16x16x32_bf16(
                       a, __builtin_bit_cast(bf16x8, bw[0][ks]), acc0, 0, 0, 0);
            acc1 = __builtin_amdgcn_mfma_f32_16x16x32_bf16(
                       a, __builtin_bit_cast(bf16x8, bw[1][ks]), acc1, 0, 0, 0);
        }

        // C/D: col = lane&15 (= o-col), row = kq*4 + r
        #pragma unroll
        for (int r = 0; r < 4; ++r) {
            int nr = mt * 16 + kq * 4 + r;
            if (nr < NHEX) {
                float* po = outb + (size_t)nr * OUTC + ow * 32 + col;
                po[0]  = acc0[r] + bias_o[0];
                po[16] = acc1[r] + bias_o[1];
            }
        }
    }
}

extern "C" void kernel_launch(void* const* d_in, const int* in_sizes, int n_in,
                              void* d_out, int out_size, void* d_ws, size_t ws_size,
                              hipStream_t stream) {
    const float* x    = (const float*)d_in[0];
    const float* W    = (const float*)d_in[1];
    const float* bias = (const float*)d_in[2];
    float* out        = (float*)d_out;

    int B = in_sizes[0] / (NHEX * HEXDIM);
    hexconv_kernel<<<B, 256, 0, stream>>>(x, W, bias, out);
}

// Round 4
// 181.452 us; speedup vs baseline: 1.1625x; 1.1625x over previous
//
#include <hip/hip_runtime.h>
#include <stdint.h>

typedef __bf16 bf16x8 __attribute__((ext_vector_type(8)));
typedef float floatx4 __attribute__((ext_vector_type(4)));
typedef uint32_t uint32x4 __attribute__((ext_vector_type(4)));

#define GRID_W   15
#define PAD_W    17
#define CELLS    221            // 13*17 padded cells
#define HEXDIM   64
#define NHEX     165
#define OUTC     64
#define KDIM     448
#define CWORDS   32             // uint32 words per cell (64 bf16)
#define SXWORDS  (CELLS * CWORDS)   // 7072 words = 28288 B

// round-to-nearest-even fp32 -> bf16, packed pair
__device__ __forceinline__ uint32_t pack2bf(float a, float b) {
    union { float f; uint32_t u; } ua, ub;
    ua.f = a; ub.f = b;
    uint32_t ra = (ua.u + 0x7fffu + ((ua.u >> 16) & 1u)) >> 16;
    uint32_t rb = (ub.u + 0x7fffu + ((ub.u >> 16) & 1u)) >> 16;
    return ra | (rb << 16);
}

// ---- prep: W fp32 -> bf16 (64*448 = 28672 elems, 7168 float4s, 28 blocks) ----
__global__ void wprep_kernel(const float* __restrict__ W, uint32_t* __restrict__ Wbf) {
    int i = blockIdx.x * 256 + threadIdx.x;   // float4 index
    float4 v = ((const float4*)W)[i];
    uint2 p; p.x = pack2bf(v.x, v.y); p.y = pack2bf(v.z, v.w);
    ((uint2*)Wbf)[i] = p;
}

__device__ __forceinline__ floatx4 mfma16(bf16x8 a, uint32x4 b, floatx4 c) {
    return __builtin_amdgcn_mfma_f32_16x16x32_bf16(a, __builtin_bit_cast(bf16x8, b), c, 0, 0, 0);
}

// Compute one 2-tile pair of partial GEMMs for K-half KH (k-steps KH*7 .. KH*7+6).
template<int KH>
__device__ __forceinline__ void pair_accs(const uint32_t* __restrict__ sx,
                                          int mtA, int mtB, int col, int kq,
                                          const uint32x4 bw[2][7],
                                          floatx4& a00, floatx4& a01,
                                          floatx4& a10, floatx4& a11)
{
    const int off0[7] = {-17, -16, -1, 0, 1, 17, 18};
    const int off1[7] = {-18, -17, -1, 0, 1, 16, 17};

    int cellA[4], cellB[4];
    #pragma unroll
    for (int two = 0; two < 2; ++two) {
        int mt = two ? mtB : mtA;
        int* cells = two ? cellB : cellA;
        int n = mt * 16 + col;
        bool valid = (n < NHEX);
        int nn = valid ? n : 0;
        int y0 = nn / GRID_W, x0 = nn - y0 * GRID_W;
        int base = (y0 + 1) * PAD_W + (x0 + 1);
        bool use0 = (y0 & 1);
        #pragma unroll
        for (int jj = 0; jj < 4; ++jj) {
            const int j = KH * 3 + jj;   // constexpr per unrolled jj
            cells[jj] = valid ? (base + (use0 ? off0[j] : off1[j])) : 16; // cell 16 = halo (0)
        }
    }

    #pragma unroll
    for (int ksl = 0; ksl < 7; ++ksl) {
        const int ks = KH * 7 + ksl;        // constexpr
        const int jj = (ks >> 1) - KH * 3;  // 0..3, constexpr
        const int h  = ks & 1;              // dim-half, constexpr
        int cA = cellA[jj], cB = cellB[jj];
        int chA = ((h * 4 + kq) ^ (cA & 7));
        int chB = ((h * 4 + kq) ^ (cB & 7));
        uint32x4 avA = *(const uint32x4*)(sx + cA * CWORDS + chA * 4); // ds_read_b128
        uint32x4 avB = *(const uint32x4*)(sx + cB * CWORDS + chB * 4);
        bf16x8 aA = __builtin_bit_cast(bf16x8, avA);
        bf16x8 aB = __builtin_bit_cast(bf16x8, avB);
        a00 = mfma16(aA, bw[0][ksl], a00);
        a10 = mfma16(aB, bw[0][ksl], a10);
        a01 = mfma16(aA, bw[1][ksl], a01);
        a11 = mfma16(aB, bw[1][ksl], a11);
    }
}

__global__ __launch_bounds__(512, 4)
void hexconv_kernel(const float* __restrict__ x,
                    const uint32_t* __restrict__ Wbf,
                    const float* __restrict__ bias,
                    float* __restrict__ out)
{
    __shared__ __align__(16) uint32_t sx[SXWORDS];          // 28,288 B
    __shared__ __align__(16) floatx4 red[2][4][4][64];      // dbuf x (mw,ow) x quad x lane: 32,768 B

    const int tid  = threadIdx.x;
    const int b    = blockIdx.x;
    const int wave = tid >> 6;
    const int lane = tid & 63;
    const int col  = lane & 15;   // A-row m / B-col (o) / C-col
    const int kq   = lane >> 4;   // k-quad
    const int kh   = wave & 1;         // K-half
    const int ow   = (wave >> 1) & 1;  // o-half: channels [ow*32, ow*32+32)
    const int mw   = wave >> 2;        // m-parity: tiles mw, mw+2, ...

    // ---- B fragments for this wave's K-half: bw[ot][ksl], 56 VGPRs ----
    uint32x4 bw[2][7];
    #pragma unroll
    for (int ot = 0; ot < 2; ++ot) {
        int o = ow * 32 + ot * 16 + col;
        const uint32_t* wp = Wbf + o * (KDIM / 2) + kh * 112 + kq * 4; // uint32 words
        #pragma unroll
        for (int ksl = 0; ksl < 7; ++ksl)
            bw[ot][ksl] = *(const uint32x4*)(wp + ksl * 16);
    }
    const float b0 = bias[ow * 32 + col];
    const float b1 = bias[ow * 32 + 16 + col];

    // ---- zero LDS grid (halo must read as 0) ----
    for (int i = tid; i < SXWORDS; i += 512) sx[i] = 0u;
    __syncthreads();

    // ---- stage sample b: fp32 global -> bf16 swizzled LDS grid ----
    {
        const float4* xs = (const float4*)(x + (size_t)b * NHEX * HEXDIM);
        for (int i = tid; i < NHEX * HEXDIM / 4; i += 512) {
            int n = i >> 4;            // hex index
            int d = i & 15;            // float4 within hex
            float4 v = xs[i];
            int y0 = n / GRID_W, x0 = n - y0 * GRID_W;
            int cell = (y0 + 1) * PAD_W + (x0 + 1);
            int pc   = (d >> 1) ^ (cell & 7);               // swizzled 16B chunk
            uint32_t* dst = sx + cell * CWORDS + pc * 4 + (d & 1) * 2;
            uint2 p; p.x = pack2bf(v.x, v.y); p.y = pack2bf(v.z, v.w);
            *(uint2*)dst = p;
        }
    }
    __syncthreads();

    // ---- main loop: 3 iterations x 2 m-tiles; K-split reduction through LDS ----
    float* outb = out + (size_t)b * NHEX * OUTC;
    const int region = mw * 2 + ow;

    #pragma unroll 1
    for (int t = 0; t < 3; ++t) {
        int mtA = mw + t * 4;
        int mtB = mtA + 2;

        floatx4 a00 = {0.f,0.f,0.f,0.f}, a01 = {0.f,0.f,0.f,0.f};
        floatx4 a10 = {0.f,0.f,0.f,0.f}, a11 = {0.f,0.f,0.f,0.f};
        if (kh == 0) pair_accs<0>(sx, mtA, mtB, col, kq, bw, a00, a01, a10, a11);
        else         pair_accs<1>(sx, mtA, mtB, col, kq, bw, a00, a01, a10, a11);

        int buf = t & 1;
        if (kh) {
            red[buf][region][0][lane] = a00;
            red[buf][region][1][lane] = a01;
            red[buf][region][2][lane] = a10;
            red[buf][region][3][lane] = a11;
        }
        __syncthreads();
        if (!kh) {
            floatx4 p0 = red[buf][region][0][lane];
            floatx4 p1 = red[buf][region][1][lane];
            floatx4 p2 = red[buf][region][2][lane];
            floatx4 p3 = red[buf][region][3][lane];
            a00 += p0; a01 += p1; a10 += p2; a11 += p3;
            #pragma unroll
            for (int rr = 0; rr < 4; ++rr) {
                int nrA = mtA * 16 + kq * 4 + rr;
                if (nrA < NHEX) {
                    float* po = outb + (size_t)nrA * OUTC + ow * 32 + col;
                    po[0]  = a00[rr] + b0;
                    po[16] = a01[rr] + b1;
                }
                int nrB = mtB * 16 + kq * 4 + rr;
                if (nrB < NHEX) {
                    float* po = outb + (size_t)nrB * OUTC + ow * 32 + col;
                    po[0]  = a10[rr] + b0;
                    po[16] = a11[rr] + b1;
                }
            }
        }
    }
}

extern "C" void kernel_launch(void* const* d_in, const int* in_sizes, int n_in,
                              void* d_out, int out_size, void* d_ws, size_t ws_size,
                              hipStream_t stream) {
    const float* x    = (const float*)d_in[0];
    const float* W    = (const float*)d_in[1];
    const float* bias = (const float*)d_in[2];
    float* out        = (float*)d_out;
    uint32_t* Wbf     = (uint32_t*)d_ws;      // 57,344 B of bf16 W

    wprep_kernel<<<28, 256, 0, stream>>>(W, Wbf);

    int B = in_sizes[0] / (NHEX * HEXDIM);
    hexconv_kernel<<<B, 512, 0, stream>>>(x, Wbf, bias, out);
}